// Round 1
// baseline (197.486 us; speedup 1.0000x reference)
//
#include <hip/hip_runtime.h>

// Problem constants (fixed by setup_inputs): B=128, BANDS=256, P=32, K=64
#define SIGMA 0.1f
#define BANDS 256
#define KSEL  64
#define GTHREADS 512   // block size (8 waves)
#define PPB      8     // planes per block (8 divides KSEL -> same b per block)

typedef float vfloat4 __attribute__((ext_vector_type(4)));

// Single fused kernel.
// Phase 1 (redundant per block, ~0.5us of LDS-broadcast VALU, hidden under
// launch/memory ramp): compute gates, rank-select top-64 with jax.lax.top_k
// tie-break (lower index wins on ties), build ascending-band-ordered
// (== jnp.sort(idx)) index+gate lists in LDS.
// Phase 2: out[b, j, :, :] = x[b, idx[j], :, :] * gate[idx[j]]
// 512 threads handle 2 planes per step, 4 steps, nontemporal (stream-once).
__global__ void __launch_bounds__(GTHREADS)
FeatureSelector_fused(const float*   __restrict__ mu,
                      const float*   __restrict__ noise,
                      const float*   __restrict__ extra,
                      const vfloat4* __restrict__ x,
                      vfloat4*       __restrict__ out) {
    __shared__ float g[BANDS];
    __shared__ unsigned long long masks[BANDS / 64];
    __shared__ int   sidx[KSEL];
    __shared__ float sgate[KSEL];

    const int tid = threadIdx.x;

    // ---- Phase 1: gates + top-k selection (threads 0..255 active) ----
    float gate = 0.0f;
    bool  sel  = false;
    unsigned long long m = 0;

    if (tid < BANDS) {
        float z = mu[tid] + SIGMA * (noise[tid] + 0.25f * extra[tid]) + 0.5f;
        gate = fminf(fmaxf(z, 0.0f), 1.0f);
        g[tid] = gate;
    }
    __syncthreads();

    if (tid < BANDS) {
        // rank = # elements that beat me (greater value, or equal w/ lower idx)
        int rank = 0;
#pragma unroll 16
        for (int j = 0; j < BANDS; ++j) {
            float gj = g[j];   // same j for all lanes -> LDS broadcast, free
            rank += (gj > gate) || (gj == gate && j < tid);
        }
        sel = rank < KSEL;
        m = __ballot(sel);     // waves 0..3 fully active here (BANDS = 4 waves)
        if ((tid & 63) == 0) masks[tid >> 6] = m;
    }
    __syncthreads();

    if (sel) {
        const int lane = tid & 63;
        const int wave = tid >> 6;
        int pos = __popcll(m & ((1ull << lane) - 1ull));
        for (int w = 0; w < wave; ++w) pos += __popcll(masks[w]);
        sidx[pos]  = tid;      // ascending band order == jnp.sort(idx)
        sgate[pos] = gate;
    }
    __syncthreads();

    // ---- Phase 2: gather + scale (all 512 threads) ----
    const int bj0 = blockIdx.x * PPB;     // first (b,j) of this block
    const int b   = bj0 >> 6;             // / KSEL
    const int j0  = bj0 & (KSEL - 1);
    const int jt  = tid >> 8;             // which of 2 planes in a step
    const int t   = tid & 255;            // float4 index within 32x32 plane

    constexpr int STEPS = PPB / 2;        // 4

    int   band[STEPS];
    float s[STEPS];
#pragma unroll
    for (int p = 0; p < STEPS; ++p) {
        band[p] = sidx[j0 + 2 * p + jt];
        s[p]    = sgate[j0 + 2 * p + jt];
    }

    vfloat4 v[STEPS];
#pragma unroll
    for (int p = 0; p < STEPS; ++p)
        v[p] = __builtin_nontemporal_load(&x[(b * BANDS + band[p]) * 256 + t]);
#pragma unroll
    for (int p = 0; p < STEPS; ++p) {
        v[p] *= s[p];
        __builtin_nontemporal_store(v[p], &out[(b * KSEL + j0 + 2 * p + jt) * 256 + t]);
    }
}

extern "C" void kernel_launch(void* const* d_in, const int* in_sizes, int n_in,
                              void* d_out, int out_size, void* d_ws, size_t ws_size,
                              hipStream_t stream) {
    const float* x     = (const float*)d_in[0];  // (128,1,256,32,32)
    const float* mu    = (const float*)d_in[1];  // (256,)
    const float* noise = (const float*)d_in[2];  // (256,)
    const float* extra = (const float*)d_in[3];  // (256,)
    // d_in[4] = k (=64), hard-coded as KSEL; d_ws unused (selection lives in LDS)

    const int B = 128;
    FeatureSelector_fused<<<(B * KSEL) / PPB, GTHREADS, 0, stream>>>(
        mu, noise, extra, (const vfloat4*)x, (vfloat4*)d_out);
}

// Round 3
// 192.305 us; speedup vs baseline: 1.0269x; 1.0269x over previous
//
#include <hip/hip_runtime.h>

// Problem constants (fixed by setup_inputs): B=128, BANDS=256, P=32, K=64
#define SIGMA 0.1f
#define BANDS 256
#define KSEL  64
#define GTHREADS 512   // gather block size
#define PPB      8     // planes per gather block (8 divides KSEL -> same b)

typedef float vfloat4 __attribute__((ext_vector_type(4)));

// Kernel 1: compute gates, select top-64 (jax.lax.top_k tie-break: lower
// index wins on equal values), emit indices sorted ascending + gathered gate
// values into workspace. Runs once (1 block); gather blocks consume ws.
// NOTE (round 1 post-mortem): fusing this into the gather kernel regressed
// +5us — the rank loop then delays the HBM ramp of all 1024 gather blocks.
// Keep it as a separate tiny dispatch, hidden under launch latency.
__global__ void FeatureSelector_topk(const float* __restrict__ mu,
                                     const float* __restrict__ noise,
                                     const float* __restrict__ extra,
                                     int*   __restrict__ ws_idx,
                                     float* __restrict__ ws_gate) {
    __shared__ float g[BANDS];
    __shared__ unsigned long long masks[BANDS / 64];
    const int tid  = threadIdx.x;
    const int wave = tid >> 6;
    const int lane = tid & 63;

    float z = mu[tid] + SIGMA * (noise[tid] + 0.25f * extra[tid]) + 0.5f;
    float gate = fminf(fmaxf(z, 0.0f), 1.0f);
    g[tid] = gate;
    __syncthreads();

    // rank = number of elements that beat me (higher value, or equal value
    // with lower index). rank < K  =>  selected.
    // float4 LDS broadcast: 64 vector iterations instead of 256 scalar.
    const vfloat4* g4 = (const vfloat4*)g;
    int rank = 0;
#pragma unroll 8
    for (int j4 = 0; j4 < BANDS / 4; ++j4) {
        vfloat4 gj = g4[j4];               // same addr all lanes -> broadcast
        int jb = j4 * 4;
        rank += (gj.x > gate) || (gj.x == gate && (jb + 0) < tid);
        rank += (gj.y > gate) || (gj.y == gate && (jb + 1) < tid);
        rank += (gj.z > gate) || (gj.z == gate && (jb + 2) < tid);
        rank += (gj.w > gate) || (gj.w == gate && (jb + 3) < tid);
    }
    const bool sel = rank < KSEL;

    unsigned long long m = __ballot(sel);
    if (lane == 0) masks[wave] = m;
    __syncthreads();

    if (sel) {
        int pos = __popcll(m & ((1ull << lane) - 1ull));
        for (int w = 0; w < wave; ++w) pos += __popcll(masks[w]);
        ws_idx[pos]  = tid;     // ascending band order == jnp.sort(idx)
        ws_gate[pos] = gate;
    }
}

// Kernel 2: out[b, j, :, :] = x[b, idx[j], :, :] * gate[idx[j]]
// 512 threads handle 2 planes per "slot"; PPB=8 planes per block.
// Each thread: 8/2 = 4 float4 loads in flight, non-temporal (stream-once).
__global__ void __launch_bounds__(GTHREADS)
FeatureSelector_gather(const vfloat4* __restrict__ x,
                       const int*     __restrict__ ws_idx,
                       const float*   __restrict__ ws_gate,
                       vfloat4*       __restrict__ out) {
    const int bj0 = blockIdx.x * PPB;     // first (b,j) of this block
    const int b   = bj0 >> 6;             // / KSEL
    const int j0  = bj0 & (KSEL - 1);
    const int tid = threadIdx.x;          // 0..511: covers 2 planes per step
    const int jt  = tid >> 8;             // which of the 2 planes in a step
    const int t   = tid & 255;            // float4 index within plane

    constexpr int STEPS = PPB / 2;        // 4

    int   band[STEPS];
    float s[STEPS];
#pragma unroll
    for (int p = 0; p < STEPS; ++p) {
        band[p] = ws_idx[j0 + 2 * p + jt];
        s[p]    = ws_gate[j0 + 2 * p + jt];
    }

    vfloat4 v[STEPS];
#pragma unroll
    for (int p = 0; p < STEPS; ++p)
        v[p] = __builtin_nontemporal_load(&x[(b * BANDS + band[p]) * 256 + t]);
#pragma unroll
    for (int p = 0; p < STEPS; ++p) {
        v[p] *= s[p];
        __builtin_nontemporal_store(v[p], &out[(b * KSEL + j0 + 2 * p + jt) * 256 + t]);
    }
}

extern "C" void kernel_launch(void* const* d_in, const int* in_sizes, int n_in,
                              void* d_out, int out_size, void* d_ws, size_t ws_size,
                              hipStream_t stream) {
    const float* x     = (const float*)d_in[0];  // (128,1,256,32,32)
    const float* mu    = (const float*)d_in[1];  // (256,)
    const float* noise = (const float*)d_in[2];  // (256,)
    const float* extra = (const float*)d_in[3];  // (256,)
    // d_in[4] = k (=64), hard-coded as KSEL

    int*   ws_idx  = (int*)d_ws;
    float* ws_gate = (float*)((char*)d_ws + KSEL * sizeof(int));

    FeatureSelector_topk<<<1, BANDS, 0, stream>>>(mu, noise, extra, ws_idx, ws_gate);

    const int B = 128;
    FeatureSelector_gather<<<(B * KSEL) / PPB, GTHREADS, 0, stream>>>(
        (const vfloat4*)x, ws_idx, ws_gate, (vfloat4*)d_out);
}